// Round 4
// baseline (528.145 us; speedup 1.0000x reference)
//
#include <hip/hip_runtime.h>
#include <math.h>

#define V 2
#define NN 100000
#define KK 8
#define DD 128
#define TILE_N 128
#define LOG2PI 1.8378770664093454f
#define LOG_1EM6 -13.815510557964274f

// ws layout (bytes):
//  whi: [16][16384] ushort  (swizzled LDS image per (v,k))   @ 0       (512 KB)
//  wlo: [16][16384] ushort                                    @ 524288 (512 KB)
//  b:   [16][128] float                                       @ 1048576 (8 KB)
//  c:   [16] float                                            @ 1056768
#define WLO_B 524288
#define BV_B  1048576
#define C_B   1056768

// out layout (floats): energies [N][V] | weights [N][V] | total_energies | total_penalty
#define OUT_W_OFF (NN*V)
#define OUT_TE (2*NN*V)
#define OUT_TP (2*NN*V + 1)

typedef __attribute__((ext_vector_type(8))) short bf16x8;
typedef __attribute__((ext_vector_type(4))) float f32x4;

__device__ __forceinline__ unsigned short f2bf_rtn(float f) {
    unsigned u = __builtin_bit_cast(unsigned, f);
    unsigned r = u + 0x7FFFu + ((u >> 16) & 1u);
    return (unsigned short)(r >> 16);
}
__device__ __forceinline__ float bf2f(unsigned short h) {
    unsigned u = ((unsigned)h) << 16;
    return __builtin_bit_cast(float, u);
}

__global__ void zero_kernel(float* out) {
    int t = threadIdx.x;
    if (t < 2) out[OUT_TE + t] = 0.0f;
}

// One block of 256 threads per (v,k).
// Panel-blocked (rank-8) register-tile Cholesky: 2 barriers per 8-column panel
// (32 total vs 128 in the rank-1 version), then 2-thread/column trsm.
__global__ __launch_bounds__(256) void prep_kernel(const float* __restrict__ phi,
                                                   const float* __restrict__ mu,
                                                   const float* __restrict__ sigma,
                                                   void* __restrict__ wsv,
                                                   float* __restrict__ out) {
    __shared__ float Lf[128 * 129];        // L row-major, stride 129 (lower + diag valid)
    __shared__ float Wcm[128 * 129];       // W col-major: Wcm[j*129+i] = W[i][j]
    __shared__ float Lp[8][132];           // current panel, col-major: Lp[c][row]
    __shared__ float Dblk[8][9];           // raw diagonal block for current panel
    __shared__ float Ldiag_s[128];
    __shared__ float mulds[128];
    __shared__ float red[256];

    const int tid = threadIdx.x;           // 0..255
    const int vk  = blockIdx.x;            // 0..15
    const int v   = vk >> 3;
    const int k   = vk & 7;
    const int R   = tid >> 4;              // tile row-block 0..15  (rows 8R..8R+7)
    const int C   = tid & 15;              // tile col-block 0..15  (cols 8C..8C+7)

    if (tid < DD) mulds[tid] = mu[vk * DD + tid];

    // Load 8x8 register tile of sigma (+1e-6 I).
    float A[8][8];
    const float* sig = sigma + (size_t)vk * DD * DD;
    float pen = 0.0f;
    #pragma unroll
    for (int a = 0; a < 8; ++a) {
        const float4* p4 = (const float4*)(sig + (size_t)(8 * R + a) * DD + 8 * C);
        float4 x = p4[0], y = p4[1];
        A[a][0] = x.x; A[a][1] = x.y; A[a][2] = x.z; A[a][3] = x.w;
        A[a][4] = y.x; A[a][5] = y.y; A[a][6] = y.z; A[a][7] = y.w;
        if (R == C) A[a][a] += 1e-6f;
    }
    if (R == C) {
        #pragma unroll
        for (int a = 0; a < 8; ++a) pen += 1.0f / (A[a][a] + 1e-12f);
    }

    // Bootstrap: publish raw diag block 0.
    if (R == 0 && C == 0) {
        #pragma unroll
        for (int a = 0; a < 8; ++a)
            #pragma unroll
            for (int b = 0; b < 8; ++b) Dblk[a][b] = A[a][b];
    }

    // penalty reduce (its barriers also make Dblk visible)
    red[tid] = pen;
    __syncthreads();
    for (int s = 128; s > 0; s >>= 1) {
        if (tid < s) red[tid] += red[tid + s];
        __syncthreads();
    }
    if (tid == 0) atomicAdd(&out[OUT_TP], red[0]);
    __syncthreads();

    // ---- 16 panel phases, 2 barriers each ----
    for (int p = 0; p < 16; ++p) {
        if (C == p && R >= p) {
            // redundant 8x8 Cholesky of the diagonal block (registers)
            float Ld[8][8];
            #pragma unroll
            for (int i = 0; i < 8; ++i)
                #pragma unroll
                for (int j = 0; j < 8; ++j) Ld[i][j] = Dblk[i][j];
            #pragma unroll
            for (int j = 0; j < 8; ++j) {
                float d = sqrtf(Ld[j][j]);
                Ld[j][j] = d;
                float inv = 1.0f / d;
                #pragma unroll
                for (int i = 0; i < 8; ++i) if (i > j) Ld[i][j] *= inv;
                #pragma unroll
                for (int c2 = 0; c2 < 8; ++c2) if (c2 > j)
                    #pragma unroll
                    for (int i = 0; i < 8; ++i) if (i >= c2)
                        Ld[i][c2] -= Ld[i][j] * Ld[c2][j];
            }
            if (R == p) {
                // diag block rows: L = Ld (lower), zero upper
                #pragma unroll
                for (int j = 0; j < 8; ++j) {
                    Ldiag_s[8 * p + j] = Ld[j][j];
                    #pragma unroll
                    for (int i = 0; i < 8; ++i) {
                        float val = (i >= j) ? Ld[i][j] : 0.0f;
                        Lp[j][8 * p + i] = val;
                        Lf[(8 * p + i) * 129 + 8 * p + j] = val;
                    }
                }
            } else {
                // panel rows 8R..8R+7: in-register forward recursion
                float Lrow[8][8];
                #pragma unroll
                for (int j = 0; j < 8; ++j) {
                    #pragma unroll
                    for (int a = 0; a < 8; ++a) {
                        float s = A[a][j];
                        #pragma unroll
                        for (int c2 = 0; c2 < 8; ++c2) if (c2 < j)
                            s -= Lrow[a][c2] * Ld[j][c2];
                        Lrow[a][j] = s / Ld[j][j];
                    }
                }
                #pragma unroll
                for (int j = 0; j < 8; ++j)
                    #pragma unroll
                    for (int a = 0; a < 8; ++a) {
                        Lp[j][8 * R + a] = Lrow[a][j];
                        Lf[(8 * R + a) * 129 + 8 * p + j] = Lrow[a][j];
                    }
            }
        }
        __syncthreads();   // panel visible

        // rank-8 trailing update (all threads; dead tiles harmless)
        #pragma unroll
        for (int c2 = 0; c2 < 8; ++c2) {
            float4 ra0 = *(const float4*)&Lp[c2][8 * R];
            float4 ra1 = *(const float4*)&Lp[c2][8 * R + 4];
            float4 rb0 = *(const float4*)&Lp[c2][8 * C];
            float4 rb1 = *(const float4*)&Lp[c2][8 * C + 4];
            float ra[8] = {ra0.x, ra0.y, ra0.z, ra0.w, ra1.x, ra1.y, ra1.z, ra1.w};
            float rb[8] = {rb0.x, rb0.y, rb0.z, rb0.w, rb1.x, rb1.y, rb1.z, rb1.w};
            #pragma unroll
            for (int a = 0; a < 8; ++a)
                #pragma unroll
                for (int b = 0; b < 8; ++b)
                    A[a][b] -= ra[a] * rb[b];
        }

        // publish next raw diag block
        if (p < 15 && R == p + 1 && C == p + 1) {
            #pragma unroll
            for (int a = 0; a < 8; ++a)
                #pragma unroll
                for (int b = 0; b < 8; ++b) Dblk[a][b] = A[a][b];
        }
        __syncthreads();   // Dblk visible / Lp free for next phase
    }

    // zero-init Wcm
    for (int i = tid; i < 128 * 129; i += 256) Wcm[i] = 0.0f;
    __syncthreads();

    // trsm: W = L^{-1}. Column j = tid>>1, parity split over p, shfl combine.
    {
        const int j = tid >> 1;
        const int par = tid & 1;
        if (par == 0) Wcm[j * 129 + j] = 1.0f / Lf[j * 129 + j];
        // wave-ordered: lanes 2j,2j+1 adjacent -> same wave; LDS ops in order
        for (int i = 1; i < DD; ++i) {
            float s = 0.0f;
            #pragma unroll 4
            for (int p = par; p < i; p += 2)
                s += Lf[i * 129 + p] * Wcm[j * 129 + p];
            s += __shfl_xor(s, 1, 64);
            if (par == 0 && i > j)
                Wcm[j * 129 + i] = -s / Lf[i * 129 + i];
        }
    }
    __syncthreads();

    // b_i = sum_j W[i][j] mu[j]
    if (tid < DD) {
        float b = 0.0f;
        for (int j2 = 0; j2 < DD; ++j2)
            b += Wcm[j2 * 129 + tid] * mulds[j2];
        ((float*)((char*)wsv + BV_B))[vk * DD + tid] = b;
    }

    // pack W -> bf16 hi/lo swizzled global image. 2 threads/row.
    {
        unsigned* whi = (unsigned*)((unsigned short*)wsv + (size_t)vk * 16384);
        unsigned* wlo = (unsigned*)((unsigned short*)((char*)wsv + WLO_B) + (size_t)vk * 16384);
        const int r = tid >> 1;
        const int half = (tid & 1) * 64;
        for (int d0 = half; d0 < half + 64; d0 += 2) {
            float f0 = Wcm[d0 * 129 + r];
            float f1 = Wcm[(d0 + 1) * 129 + r];
            unsigned short h0 = f2bf_rtn(f0);
            unsigned short h1 = f2bf_rtn(f1);
            unsigned short l0 = f2bf_rtn(f0 - bf2f(h0));
            unsigned short l1 = f2bf_rtn(f1 - bf2f(h1));
            int g = d0 >> 3, e = d0 & 7;
            int idx = r * 128 + ((g ^ (r & 7)) << 3) + e;   // even
            whi[idx >> 1] = (unsigned)h0 | ((unsigned)h1 << 16);
            wlo[idx >> 1] = (unsigned)l0 | ((unsigned)l1 << 16);
        }
    }

    // logdet = 2 sum log L_jj (clipped at log 1e-6)
    red[tid] = (tid < DD) ? 2.0f * logf(Ldiag_s[tid]) : 0.0f;
    __syncthreads();
    for (int s = 128; s > 0; s >>= 1) {
        if (tid < s) red[tid] += red[tid + s];
        __syncthreads();
    }
    if (tid == 0) {
        float logdet_c = fmaxf(red[0], LOG_1EM6);
        const float* ph = phi + v * KK;
        float m = ph[0];
        for (int i = 1; i < KK; ++i) m = fmaxf(m, ph[i]);
        float s = 0.0f;
        for (int i = 0; i < KK; ++i) s += expf(ph[i] - m);
        float logpi = ph[k] - m - logf(s);
        ((float*)((char*)wsv + C_B))[vk] = logpi - 0.5f * logdet_c - 0.5f * (float)DD * LOG2PI;
    }
}

// Main: block = 128 samples x 128 W-rows; wave tile 32x128; z frags in registers,
// W staged in LDS via global_load_lds (pre-swizzled); split-bf16 3-pass MFMA.
// W is lower-triangular: tiles with nt < 2*ds are exactly zero -> skipped (37.5% cut).
__global__ __launch_bounds__(256, 2) void energy_kernel(const float* __restrict__ z,
                                                        const void* __restrict__ wsv,
                                                        float* __restrict__ out) {
    __shared__ unsigned short wl[32768];     // hi [0..16384) ushorts, lo [16384..32768)
    __shared__ float maha_s[TILE_N][KK + 1];
    __shared__ float bl_s[DD];
    __shared__ float clds[V * KK];
    __shared__ float elds[TILE_N][V];
    __shared__ float red[256];

    const int tid  = threadIdx.x;
    const int lane = tid & 63;
    const int wave = tid >> 6;
    const int quad = lane >> 4;
    const int l16  = lane & 15;
    const int n0   = blockIdx.x * TILE_N;

    const unsigned short* whi_g = (const unsigned short*)wsv;
    const unsigned short* wlo_g = (const unsigned short*)((const char*)wsv + WLO_B);
    const float* b_g = (const float*)((const char*)wsv + BV_B);
    const float* c_g = (const float*)((const char*)wsv + C_B);

    if (tid < V * KK) clds[tid] = c_g[tid];

    float esum = 0.0f;

    for (int v = 0; v < V; ++v) {
        // z fragments -> registers (bf16 hi/lo split)
        bf16x8 zhi[2][4], zlo[2][4];
        #pragma unroll
        for (int mt = 0; mt < 2; ++mt) {
            int n = n0 + wave * 32 + mt * 16 + l16;
            bool ok = (n < NN);
            const float* zp = z + ((size_t)v * NN + n) * DD + quad * 8;
            #pragma unroll
            for (int ds = 0; ds < 4; ++ds) {
                float f[8];
                if (ok) {
                    float4 a  = *(const float4*)(zp + ds * 32);
                    float4 bq = *(const float4*)(zp + ds * 32 + 4);
                    f[0] = a.x;  f[1] = a.y;  f[2] = a.z;  f[3] = a.w;
                    f[4] = bq.x; f[5] = bq.y; f[6] = bq.z; f[7] = bq.w;
                } else {
                    #pragma unroll
                    for (int e = 0; e < 8; ++e) f[e] = 0.0f;
                }
                bf16x8 hi8, lo8;
                #pragma unroll
                for (int e = 0; e < 8; ++e) {
                    unsigned short hu = f2bf_rtn(f[e]);
                    unsigned short lu = f2bf_rtn(f[e] - bf2f(hu));
                    hi8[e] = (short)hu;
                    lo8[e] = (short)lu;
                }
                zhi[mt][ds] = hi8;
                zlo[mt][ds] = lo8;
            }
        }

        for (int k = 0; k < KK; ++k) {
            const int vk = v * KK + k;
            __syncthreads();   // previous compute done; wl free
            // stage W hi+lo (64 KB) flat into LDS
            {
                const char* srch = (const char*)(whi_g + (size_t)vk * 16384);
                const char* srcl = (const char*)(wlo_g + (size_t)vk * 16384);
                char* ldsbase = (char*)wl;
                const int lane_off = wave * 1024 + lane * 16;
                #pragma unroll
                for (int t = 0; t < 8; ++t)
                    __builtin_amdgcn_global_load_lds(
                        (const __attribute__((address_space(1))) void*)(srch + t * 4096 + lane_off),
                        (__attribute__((address_space(3))) void*)(ldsbase + t * 4096 + wave * 1024),
                        16, 0, 0);
                #pragma unroll
                for (int t = 0; t < 8; ++t)
                    __builtin_amdgcn_global_load_lds(
                        (const __attribute__((address_space(1))) void*)(srcl + t * 4096 + lane_off),
                        (__attribute__((address_space(3))) void*)(ldsbase + 32768 + t * 4096 + wave * 1024),
                        16, 0, 0);
            }
            if (tid < DD) bl_s[tid] = b_g[vk * DD + tid];
            __syncthreads();   // drains vmcnt (global_load_lds) + lgkm

            f32x4 acc[2][8];
            #pragma unroll
            for (int mt = 0; mt < 2; ++mt)
                #pragma unroll
                for (int nt = 0; nt < 8; ++nt)
                    acc[mt][nt] = (f32x4)(0.0f);

            #pragma unroll
            for (int ds = 0; ds < 4; ++ds) {
                const int g = ds * 4 + quad;
                #pragma unroll
                for (int nt = 0; nt < 8; ++nt) {
                    if (nt < 2 * ds) continue;   // W tile exactly zero (lower-triangular)
                    int row = nt * 16 + l16;
                    int off = row * 128 + ((g ^ (row & 7)) << 3);
                    bf16x8 bh  = *(const bf16x8*)&wl[off];
                    bf16x8 blo = *(const bf16x8*)&wl[16384 + off];
                    #pragma unroll
                    for (int mt = 0; mt < 2; ++mt) {
                        acc[mt][nt] = __builtin_amdgcn_mfma_f32_16x16x32_bf16(zhi[mt][ds], bh,  acc[mt][nt], 0, 0, 0);
                        acc[mt][nt] = __builtin_amdgcn_mfma_f32_16x16x32_bf16(zhi[mt][ds], blo, acc[mt][nt], 0, 0, 0);
                        acc[mt][nt] = __builtin_amdgcn_mfma_f32_16x16x32_bf16(zlo[mt][ds], bh,  acc[mt][nt], 0, 0, 0);
                    }
                }
            }

            // epilogue: maha[n][k] = sum_rows (y - b)^2 via quad-group shfl reduce
            #pragma unroll
            for (int mt = 0; mt < 2; ++mt) {
                float p[4] = {0.f, 0.f, 0.f, 0.f};
                #pragma unroll
                for (int nt = 0; nt < 8; ++nt) {
                    float bc = bl_s[nt * 16 + l16];
                    f32x4 a = acc[mt][nt];
                    float y0 = a[0] - bc, y1 = a[1] - bc, y2 = a[2] - bc, y3 = a[3] - bc;
                    p[0] += y0 * y0; p[1] += y1 * y1; p[2] += y2 * y2; p[3] += y3 * y3;
                }
                #pragma unroll
                for (int reg = 0; reg < 4; ++reg) {
                    float s = p[reg];
                    s += __shfl_xor(s, 1, 64);
                    s += __shfl_xor(s, 2, 64);
                    s += __shfl_xor(s, 4, 64);
                    s += __shfl_xor(s, 8, 64);
                    if (l16 == 0)
                        maha_s[wave * 32 + mt * 16 + quad * 4 + reg][k] = s;
                }
            }
        }  // k
        __syncthreads();  // maha complete

        if (tid < TILE_N && (n0 + tid) < NN) {
            float lp[KK];
            float m = -1e30f;
            #pragma unroll
            for (int k = 0; k < KK; ++k) {
                lp[k] = -0.5f * maha_s[tid][k] + clds[v * KK + k];
                m = fmaxf(m, lp[k]);
            }
            float s = 0.0f;
            #pragma unroll
            for (int k = 0; k < KK; ++k) s += expf(lp[k] - m);
            float e = -(m + logf(s));
            elds[tid][v] = e;
            esum += e;
        }
    }  // v
    __syncthreads();

    if (tid < TILE_N && (n0 + tid) < NN) {
        int n = n0 + tid;
        float e0 = elds[tid][0];
        float e1 = elds[tid][1];
        float m = fmaxf(-e0, -e1);
        float x0 = expf(-e0 - m);
        float x1 = expf(-e1 - m);
        float inv = 1.0f / (x0 + x1);
        out[(size_t)n * V + 0] = e0;
        out[(size_t)n * V + 1] = e1;
        out[OUT_W_OFF + (size_t)n * V + 0] = x0 * inv;
        out[OUT_W_OFF + (size_t)n * V + 1] = x1 * inv;
    }

    red[tid] = esum;
    __syncthreads();
    for (int s = 128; s > 0; s >>= 1) {
        if (tid < s) red[tid] += red[tid + s];
        __syncthreads();
    }
    if (tid == 0) atomicAdd(&out[OUT_TE], red[0]);
}

extern "C" void kernel_launch(void* const* d_in, const int* in_sizes, int n_in,
                              void* d_out, int out_size, void* d_ws, size_t ws_size,
                              hipStream_t stream) {
    const float* z     = (const float*)d_in[0];
    const float* phi   = (const float*)d_in[1];
    const float* mu    = (const float*)d_in[2];
    const float* sigma = (const float*)d_in[3];
    float* out = (float*)d_out;

    hipLaunchKernelGGL(zero_kernel, dim3(1), dim3(64), 0, stream, out);
    hipLaunchKernelGGL(prep_kernel, dim3(V * KK), dim3(256), 0, stream, phi, mu, sigma, d_ws, out);
    int nblocks = (NN + TILE_N - 1) / TILE_N;
    hipLaunchKernelGGL(energy_kernel, dim3(nblocks), dim3(256), 0, stream, z, d_ws, out);
}

// Round 5
// 414.548 us; speedup vs baseline: 1.2740x; 1.2740x over previous
//
#include <hip/hip_runtime.h>
#include <math.h>

#define V 2
#define NN 100000
#define KK 8
#define DD 128
#define TILE_N 128
#define SL 132
#define LOG2PI 1.8378770664093454f
#define LOG_1EM6 -13.815510557964274f

// ws layout (bytes):
//  whi: [16][16384] ushort  (swizzled LDS image per (v,k))   @ 0       (512 KB)
//  wlo: [16][16384] ushort                                    @ 524288 (512 KB)
//  b:   [16][128] float                                       @ 1048576 (8 KB)
//  c:   [16] float                                            @ 1056768
#define WLO_B 524288
#define BV_B  1048576
#define C_B   1056768

// out layout (floats): energies [N][V] | weights [N][V] | total_energies | total_penalty
#define OUT_W_OFF (NN*V)
#define OUT_TE (2*NN*V)
#define OUT_TP (2*NN*V + 1)

typedef __attribute__((ext_vector_type(8))) short bf16x8;
typedef __attribute__((ext_vector_type(4))) float f32x4;

__device__ __forceinline__ unsigned short f2bf_rtn(float f) {
    unsigned u = __builtin_bit_cast(unsigned, f);
    unsigned r = u + 0x7FFFu + ((u >> 16) & 1u);
    return (unsigned short)(r >> 16);
}
__device__ __forceinline__ float bf2f(unsigned short h) {
    unsigned u = ((unsigned)h) << 16;
    return __builtin_bit_cast(float, u);
}

__global__ void zero_kernel(float* out) {
    int t = threadIdx.x;
    if (t < 2) out[OUT_TE + t] = 0.0f;
}

// One block of 256 threads per (v,k).
// 16 panel phases; wave0 factors each 8-col panel wave-synchronously (no block
// barriers inside); rank-8 register-tile trailing update; restricted float4 trsm.
__global__ __launch_bounds__(256) void prep_kernel(const float* __restrict__ phi,
                                                   const float* __restrict__ mu,
                                                   const float* __restrict__ sigma,
                                                   void* __restrict__ wsv,
                                                   float* __restrict__ out) {
    __shared__ float Lf[DD * SL];          // L row-major, stride 132 (upper zeroed)
    __shared__ float Wcm[DD * SL];         // W col-major: Wcm[j*SL+i] = W[i][j]
    __shared__ float P[8][SL];             // current panel, col-major
    __shared__ float dvec[DD];             // raw pivots d_c = L_cc^2
    __shared__ float mulds[DD];
    __shared__ float red[256];
    __shared__ float Bv[8];

    const int tid = threadIdx.x;           // 0..255
    const int vk  = blockIdx.x;            // 0..15
    const int v   = vk >> 3;
    const int k   = vk & 7;
    const int R   = tid >> 4;              // tile rows 8R..8R+7
    const int C   = tid & 15;              // tile cols 8C..8C+7

    if (tid < DD) mulds[tid] = mu[vk * DD + tid];

    // Load 8x8 register tile of sigma (+1e-6 I).
    float A[8][8];
    const float* sig = sigma + (size_t)vk * DD * DD;
    float pen = 0.0f;
    #pragma unroll
    for (int a = 0; a < 8; ++a) {
        const float4* p4 = (const float4*)(sig + (size_t)(8 * R + a) * DD + 8 * C);
        float4 x = p4[0], y = p4[1];
        A[a][0] = x.x; A[a][1] = x.y; A[a][2] = x.z; A[a][3] = x.w;
        A[a][4] = y.x; A[a][5] = y.y; A[a][6] = y.z; A[a][7] = y.w;
        if (R == C) A[a][a] += 1e-6f;
    }
    if (R == C) {
        #pragma unroll
        for (int a = 0; a < 8; ++a) pen += 1.0f / (A[a][a] + 1e-12f);
    }

    // zero Lf (so float4 tails hit exact zeros) and Wcm
    for (int i = tid; i < DD * SL; i += 256) { Lf[i] = 0.0f; Wcm[i] = 0.0f; }

    // penalty reduce
    red[tid] = pen;
    __syncthreads();
    for (int s = 128; s > 0; s >>= 1) {
        if (tid < s) red[tid] += red[tid + s];
        __syncthreads();
    }
    if (tid == 0) atomicAdd(&out[OUT_TP], red[0]);
    __syncthreads();

    // ---- 16 panel phases ----
    for (int p = 0; p < 16; ++p) {
        // publish raw panel (cols 8p..8p+7, rows >= 8p)
        if (C == p && R >= p) {
            #pragma unroll
            for (int b = 0; b < 8; ++b) {
                *(float4*)&P[b][8 * R]     = make_float4(A[0][b], A[1][b], A[2][b], A[3][b]);
                *(float4*)&P[b][8 * R + 4] = make_float4(A[4][b], A[5][b], A[6][b], A[7][b]);
            }
        }
        __syncthreads();

        // wave0: factor the panel wave-synchronously
        if (tid < 64) {
            const int lane = tid;
            const int r1 = 8 * p + lane;
            const int r2 = r1 + 64;
            const bool ok2 = (r2 < DD);
            float pr1[8], pr2[8], rs[8];
            #pragma unroll
            for (int j = 0; j < 8; ++j) {
                pr1[j] = (r1 < DD) ? P[j][r1] : 0.0f;
                pr2[j] = ok2 ? P[j][r2] : 0.0f;
            }
            #pragma unroll
            for (int j = 0; j < 8; ++j) {
                if (lane >= j && lane < 8) Bv[lane] = pr1[j];
                __builtin_amdgcn_wave_barrier();
                float bv[8];
                #pragma unroll
                for (int m = 0; m < 8; ++m) bv[m] = Bv[m];
                __builtin_amdgcn_wave_barrier();
                float piv = bv[j];
                if (lane == j) dvec[8 * p + j] = piv;
                float inv2 = 1.0f / piv;
                rs[j] = rsqrtf(piv);
                float m1 = pr1[j] * inv2;
                float m2 = pr2[j] * inv2;
                #pragma unroll
                for (int j2 = 0; j2 < 8; ++j2) {
                    if (j2 > j) {
                        if (lane > j) pr1[j2] -= m1 * bv[j2];
                        pr2[j2] -= m2 * bv[j2];
                    }
                }
            }
            // writeback scaled L panel (zeros above diag)
            #pragma unroll
            for (int j = 0; j < 8; ++j) {
                if (r1 < DD) {
                    float v1 = (lane >= j) ? pr1[j] * rs[j] : 0.0f;
                    P[j][r1] = v1;
                    Lf[r1 * SL + 8 * p + j] = v1;
                }
                if (ok2) {
                    float v2 = pr2[j] * rs[j];
                    P[j][r2] = v2;
                    Lf[r2 * SL + 8 * p + j] = v2;
                }
            }
        }
        __syncthreads();

        // rank-8 trailing update
        if (C > p && R >= p) {
            #pragma unroll
            for (int j = 0; j < 8; ++j) {
                float4 a0 = *(const float4*)&P[j][8 * R];
                float4 a1 = *(const float4*)&P[j][8 * R + 4];
                float4 b0 = *(const float4*)&P[j][8 * C];
                float4 b1 = *(const float4*)&P[j][8 * C + 4];
                float ra[8] = {a0.x, a0.y, a0.z, a0.w, a1.x, a1.y, a1.z, a1.w};
                float rb[8] = {b0.x, b0.y, b0.z, b0.w, b1.x, b1.y, b1.z, b1.w};
                #pragma unroll
                for (int a = 0; a < 8; ++a)
                    #pragma unroll
                    for (int b = 0; b < 8; ++b)
                        A[a][b] -= ra[a] * rb[b];
            }
        }
        __syncthreads();
    }

    // trsm: W = L^{-1}. Thread pair per column; i from j+1; aligned float4 reads.
    {
        const int j = tid >> 1;
        const int par = tid & 1;
        if (par == 0) Wcm[j * SL + j] = 1.0f / Lf[j * SL + j];
        __builtin_amdgcn_wave_barrier();
        const int pj0 = (j & ~3) + 4 * par;
        for (int i = j + 1; i < DD; ++i) {
            float s = 0.0f;
            for (int p4 = pj0; p4 < i; p4 += 8) {
                float4 lf = *(const float4*)&Lf[i * SL + p4];
                float4 wc = *(const float4*)&Wcm[j * SL + p4];
                s += lf.x * wc.x + lf.y * wc.y + lf.z * wc.z + lf.w * wc.w;
            }
            s += __shfl_xor(s, 1, 64);
            if (par == 0)
                Wcm[j * SL + i] = -s / Lf[i * SL + i];
        }
    }
    __syncthreads();

    // b_i = sum_j W[i][j] mu[j]
    if (tid < DD) {
        float b = 0.0f;
        for (int j2 = 0; j2 < DD; ++j2)
            b += Wcm[j2 * SL + tid] * mulds[j2];
        ((float*)((char*)wsv + BV_B))[vk * DD + tid] = b;
    }

    // pack W -> bf16 hi/lo swizzled global image. 2 threads/row.
    {
        unsigned* whi = (unsigned*)((unsigned short*)wsv + (size_t)vk * 16384);
        unsigned* wlo = (unsigned*)((unsigned short*)((char*)wsv + WLO_B) + (size_t)vk * 16384);
        const int r = tid >> 1;
        const int half = (tid & 1) * 64;
        for (int d0 = half; d0 < half + 64; d0 += 2) {
            float f0 = Wcm[d0 * SL + r];
            float f1 = Wcm[(d0 + 1) * SL + r];
            unsigned short h0 = f2bf_rtn(f0);
            unsigned short h1 = f2bf_rtn(f1);
            unsigned short l0 = f2bf_rtn(f0 - bf2f(h0));
            unsigned short l1 = f2bf_rtn(f1 - bf2f(h1));
            int g = d0 >> 3, e = d0 & 7;
            int idx = r * 128 + ((g ^ (r & 7)) << 3) + e;   // even
            whi[idx >> 1] = (unsigned)h0 | ((unsigned)h1 << 16);
            wlo[idx >> 1] = (unsigned)l0 | ((unsigned)l1 << 16);
        }
    }

    // logdet = sum log d_c (clipped at log 1e-6)
    red[tid] = (tid < DD) ? logf(dvec[tid]) : 0.0f;
    __syncthreads();
    for (int s = 128; s > 0; s >>= 1) {
        if (tid < s) red[tid] += red[tid + s];
        __syncthreads();
    }
    if (tid == 0) {
        float logdet_c = fmaxf(red[0], LOG_1EM6);
        const float* ph = phi + v * KK;
        float m = ph[0];
        for (int i = 1; i < KK; ++i) m = fmaxf(m, ph[i]);
        float s = 0.0f;
        for (int i = 0; i < KK; ++i) s += expf(ph[i] - m);
        float logpi = ph[k] - m - logf(s);
        ((float*)((char*)wsv + C_B))[vk] = logpi - 0.5f * logdet_c - 0.5f * (float)DD * LOG2PI;
    }
}

// Main: block = 128 samples x 128 W-rows; wave tile 32x128; z frags in registers,
// W staged in LDS via global_load_lds (pre-swizzled); split-bf16 3-pass MFMA.
// W is lower-triangular: tiles with nt < 2*ds are exactly zero -> skipped.
__global__ __launch_bounds__(256, 2) void energy_kernel(const float* __restrict__ z,
                                                        const void* __restrict__ wsv,
                                                        float* __restrict__ out) {
    __shared__ unsigned short wl[32768];     // hi [0..16384) ushorts, lo [16384..32768)
    __shared__ float maha_s[TILE_N][KK + 1];
    __shared__ float bl_s[DD];
    __shared__ float clds[V * KK];
    __shared__ float elds[TILE_N][V];
    __shared__ float red[256];

    const int tid  = threadIdx.x;
    const int lane = tid & 63;
    const int wave = tid >> 6;
    const int quad = lane >> 4;
    const int l16  = lane & 15;
    const int n0   = blockIdx.x * TILE_N;

    const unsigned short* whi_g = (const unsigned short*)wsv;
    const unsigned short* wlo_g = (const unsigned short*)((const char*)wsv + WLO_B);
    const float* b_g = (const float*)((const char*)wsv + BV_B);
    const float* c_g = (const float*)((const char*)wsv + C_B);

    if (tid < V * KK) clds[tid] = c_g[tid];

    float esum = 0.0f;

    for (int v = 0; v < V; ++v) {
        // z fragments -> registers (bf16 hi/lo split)
        bf16x8 zhi[2][4], zlo[2][4];
        #pragma unroll
        for (int mt = 0; mt < 2; ++mt) {
            int n = n0 + wave * 32 + mt * 16 + l16;
            bool ok = (n < NN);
            const float* zp = z + ((size_t)v * NN + n) * DD + quad * 8;
            #pragma unroll
            for (int ds = 0; ds < 4; ++ds) {
                float f[8];
                if (ok) {
                    float4 a  = *(const float4*)(zp + ds * 32);
                    float4 bq = *(const float4*)(zp + ds * 32 + 4);
                    f[0] = a.x;  f[1] = a.y;  f[2] = a.z;  f[3] = a.w;
                    f[4] = bq.x; f[5] = bq.y; f[6] = bq.z; f[7] = bq.w;
                } else {
                    #pragma unroll
                    for (int e = 0; e < 8; ++e) f[e] = 0.0f;
                }
                bf16x8 hi8, lo8;
                #pragma unroll
                for (int e = 0; e < 8; ++e) {
                    unsigned short hu = f2bf_rtn(f[e]);
                    unsigned short lu = f2bf_rtn(f[e] - bf2f(hu));
                    hi8[e] = (short)hu;
                    lo8[e] = (short)lu;
                }
                zhi[mt][ds] = hi8;
                zlo[mt][ds] = lo8;
            }
        }

        for (int k = 0; k < KK; ++k) {
            const int vk = v * KK + k;
            __syncthreads();   // previous compute done; wl free
            // stage W hi+lo (64 KB) flat into LDS
            {
                const char* srch = (const char*)(whi_g + (size_t)vk * 16384);
                const char* srcl = (const char*)(wlo_g + (size_t)vk * 16384);
                char* ldsbase = (char*)wl;
                const int lane_off = wave * 1024 + lane * 16;
                #pragma unroll
                for (int t = 0; t < 8; ++t)
                    __builtin_amdgcn_global_load_lds(
                        (const __attribute__((address_space(1))) void*)(srch + t * 4096 + lane_off),
                        (__attribute__((address_space(3))) void*)(ldsbase + t * 4096 + wave * 1024),
                        16, 0, 0);
                #pragma unroll
                for (int t = 0; t < 8; ++t)
                    __builtin_amdgcn_global_load_lds(
                        (const __attribute__((address_space(1))) void*)(srcl + t * 4096 + lane_off),
                        (__attribute__((address_space(3))) void*)(ldsbase + 32768 + t * 4096 + wave * 1024),
                        16, 0, 0);
            }
            if (tid < DD) bl_s[tid] = b_g[vk * DD + tid];
            __syncthreads();   // drains vmcnt (global_load_lds) + lgkm

            f32x4 acc[2][8];
            #pragma unroll
            for (int mt = 0; mt < 2; ++mt)
                #pragma unroll
                for (int nt = 0; nt < 8; ++nt)
                    acc[mt][nt] = (f32x4)(0.0f);

            #pragma unroll
            for (int ds = 0; ds < 4; ++ds) {
                const int g = ds * 4 + quad;
                #pragma unroll
                for (int nt = 0; nt < 8; ++nt) {
                    if (nt < 2 * ds) continue;   // W tile exactly zero (lower-triangular)
                    int row = nt * 16 + l16;
                    int off = row * 128 + ((g ^ (row & 7)) << 3);
                    bf16x8 bh  = *(const bf16x8*)&wl[off];
                    bf16x8 blo = *(const bf16x8*)&wl[16384 + off];
                    #pragma unroll
                    for (int mt = 0; mt < 2; ++mt) {
                        acc[mt][nt] = __builtin_amdgcn_mfma_f32_16x16x32_bf16(zhi[mt][ds], bh,  acc[mt][nt], 0, 0, 0);
                        acc[mt][nt] = __builtin_amdgcn_mfma_f32_16x16x32_bf16(zhi[mt][ds], blo, acc[mt][nt], 0, 0, 0);
                        acc[mt][nt] = __builtin_amdgcn_mfma_f32_16x16x32_bf16(zlo[mt][ds], bh,  acc[mt][nt], 0, 0, 0);
                    }
                }
            }

            // epilogue: maha[n][k] = sum_rows (y - b)^2 via quad-group shfl reduce
            #pragma unroll
            for (int mt = 0; mt < 2; ++mt) {
                float p[4] = {0.f, 0.f, 0.f, 0.f};
                #pragma unroll
                for (int nt = 0; nt < 8; ++nt) {
                    float bc = bl_s[nt * 16 + l16];
                    f32x4 a = acc[mt][nt];
                    float y0 = a[0] - bc, y1 = a[1] - bc, y2 = a[2] - bc, y3 = a[3] - bc;
                    p[0] += y0 * y0; p[1] += y1 * y1; p[2] += y2 * y2; p[3] += y3 * y3;
                }
                #pragma unroll
                for (int reg = 0; reg < 4; ++reg) {
                    float s = p[reg];
                    s += __shfl_xor(s, 1, 64);
                    s += __shfl_xor(s, 2, 64);
                    s += __shfl_xor(s, 4, 64);
                    s += __shfl_xor(s, 8, 64);
                    if (l16 == 0)
                        maha_s[wave * 32 + mt * 16 + quad * 4 + reg][k] = s;
                }
            }
        }  // k
        __syncthreads();  // maha complete

        if (tid < TILE_N && (n0 + tid) < NN) {
            float lp[KK];
            float m = -1e30f;
            #pragma unroll
            for (int k = 0; k < KK; ++k) {
                lp[k] = -0.5f * maha_s[tid][k] + clds[v * KK + k];
                m = fmaxf(m, lp[k]);
            }
            float s = 0.0f;
            #pragma unroll
            for (int k = 0; k < KK; ++k) s += expf(lp[k] - m);
            float e = -(m + logf(s));
            elds[tid][v] = e;
            esum += e;
        }
    }  // v
    __syncthreads();

    if (tid < TILE_N && (n0 + tid) < NN) {
        int n = n0 + tid;
        float e0 = elds[tid][0];
        float e1 = elds[tid][1];
        float m = fmaxf(-e0, -e1);
        float x0 = expf(-e0 - m);
        float x1 = expf(-e1 - m);
        float inv = 1.0f / (x0 + x1);
        out[(size_t)n * V + 0] = e0;
        out[(size_t)n * V + 1] = e1;
        out[OUT_W_OFF + (size_t)n * V + 0] = x0 * inv;
        out[OUT_W_OFF + (size_t)n * V + 1] = x1 * inv;
    }

    red[tid] = esum;
    __syncthreads();
    for (int s = 128; s > 0; s >>= 1) {
        if (tid < s) red[tid] += red[tid + s];
        __syncthreads();
    }
    if (tid == 0) atomicAdd(&out[OUT_TE], red[0]);
}

extern "C" void kernel_launch(void* const* d_in, const int* in_sizes, int n_in,
                              void* d_out, int out_size, void* d_ws, size_t ws_size,
                              hipStream_t stream) {
    const float* z     = (const float*)d_in[0];
    const float* phi   = (const float*)d_in[1];
    const float* mu    = (const float*)d_in[2];
    const float* sigma = (const float*)d_in[3];
    float* out = (float*)d_out;

    hipLaunchKernelGGL(zero_kernel, dim3(1), dim3(64), 0, stream, out);
    hipLaunchKernelGGL(prep_kernel, dim3(V * KK), dim3(256), 0, stream, phi, mu, sigma, d_ws, out);
    int nblocks = (NN + TILE_N - 1) / TILE_N;
    hipLaunchKernelGGL(energy_kernel, dim3(nblocks), dim3(256), 0, stream, z, d_ws, out);
}